// Round 16
// baseline (275.321 us; speedup 1.0000x reference)
//
#include <hip/hip_runtime.h>
#include <hip/hip_bf16.h>

// SO3Conv restructured (see R7-R13 journal):
//   PT_l[(yo,v)][(x,u)] = psi_l scaled, bf16 ; A_l[(b,i)][(x,u)] = x, bf16
//   Y_l = A_l . PT_l^T  via mfma_f32_16x16x32_bf16
// l=0..5, d=2l+1, off_l = {0,1,10,35,84,165}.
// THIS ROUND: main_gemm = R8-proven dbuf structure + template-D epilogue
// (passing kernel), PLUS two ablation dispatches (ab_stage / ab_comp) that
// write only to dead workspace — rocprof per-dispatch rows split the 110us.

#define NT 256
typedef __bf16 bf16x8 __attribute__((ext_vector_type(8)));
typedef float f32x4 __attribute__((ext_vector_type(4)));
typedef unsigned int u32;

__device__ __forceinline__ void gload_lds16(const void* g, void* l) {
  __builtin_amdgcn_global_load_lds(
      (const __attribute__((address_space(1))) u32*)g,
      (__attribute__((address_space(3))) u32*)l, 16, 0, 0);
}

__device__ __forceinline__ void decode_s(int s, int& off, int& d) {
  if (s >= 165)      { off = 165; d = 11; }
  else if (s >= 84)  { off = 84;  d = 9; }
  else if (s >= 35)  { off = 35;  d = 7; }
  else if (s >= 10)  { off = 10;  d = 5; }
  else if (s >= 1)   { off = 1;   d = 3; }
  else               { off = 0;   d = 1; }
}

// ---------------------------------------------------------------------------
// Kernel 0: prep_all (7936 blocks): wb=bf16(w); DT=bf16(D^T) padded; build_A.
// ---------------------------------------------------------------------------
template<int D, int OFF>
__device__ __forceinline__ void build_one(const float* __restrict__ X,
                                          __hip_bfloat16* __restrict__ A,
                                          int b, __hip_bfloat16* sm) {
  const float* src = X + (size_t)b * (128 * 286) + OFF;
  for (int e = threadIdx.x; e < 128 * D * D; e += NT) {
    const int x = e / (D * D), r = e - x * (D * D);
    sm[e] = __float2bfloat16(src[x * 286 + r]);
  }
  __syncthreads();
  __hip_bfloat16* dst = A + (size_t)65536 * OFF + (size_t)b * (D * 128 * D);
  for (int o = threadIdx.x; o < D * 128 * D; o += NT) {
    const int i = o / (128 * D);
    const int rem = o - i * (128 * D);
    const int x = rem / D, u = rem - x * D;
    dst[o] = sm[x * D * D + u * D + i];
  }
}

__global__ __launch_bounds__(NT)
void prep_all(const float* __restrict__ w, const float* __restrict__ Dm,
              const float* __restrict__ X,
              __hip_bfloat16* __restrict__ wb, __hip_bfloat16* __restrict__ DT,
              __hip_bfloat16* __restrict__ A) {
  __shared__ __hip_bfloat16 sm[128 * 121];
  const int bx = blockIdx.x;
  if (bx < 4096) {
    const int t = bx * NT + threadIdx.x;
    const float4 a = reinterpret_cast<const float4*>(w)[t * 2];
    const float4 b = reinterpret_cast<const float4*>(w)[t * 2 + 1];
    __hip_bfloat16 v[8];
    v[0] = __float2bfloat16(a.x); v[1] = __float2bfloat16(a.y);
    v[2] = __float2bfloat16(a.z); v[3] = __float2bfloat16(a.w);
    v[4] = __float2bfloat16(b.x); v[5] = __float2bfloat16(b.y);
    v[6] = __float2bfloat16(b.z); v[7] = __float2bfloat16(b.w);
    *reinterpret_cast<bf16x8*>(&wb[t * 8]) = *reinterpret_cast<bf16x8*>(v);
  } else if (bx < 4864) {
    const int e = (bx - 4096) * NT + threadIdx.x;  // 196,608 = 384*512
    const int s = e >> 9, g = e & 511;
    DT[e] = (s < 286) ? __float2bfloat16(Dm[g * 286 + s]) : __float2bfloat16(0.0f);
  } else {
    const int b2 = bx - 4864;
    if (b2 < 512)       build_one<11, 165>(X, A, b2, sm);
    else if (b2 < 1024) build_one<9, 84>(X, A, b2 - 512, sm);
    else if (b2 < 1536) build_one<7, 35>(X, A, b2 - 1024, sm);
    else if (b2 < 2048) build_one<5, 10>(X, A, b2 - 1536, sm);
    else if (b2 < 2560) build_one<3, 1>(X, A, b2 - 2048, sm);
    else                build_one<1, 0>(X, A, b2 - 2560, sm);
  }
}

// ---------------------------------------------------------------------------
// Shared helpers (proven R7/R8 structure).
// ---------------------------------------------------------------------------
__device__ __forceinline__ void stage_tile(
    const __hip_bfloat16* __restrict__ Ap, const __hip_bfloat16* __restrict__ Bp,
    int LDK, int ktv, int m0, int n0, int tid, int wave,
    __hip_bfloat16* sA, __hip_bfloat16* sB) {
#pragma unroll
  for (int c = 0; c < 4; ++c) {
    const int q = c * 256 + tid;
    const int row = q >> 3, slot = q & 7;
    const int scol = ((slot ^ (row & 7)) << 3);
    gload_lds16(&Ap[(m0 + row) * LDK + ktv + scol], &sA[(c * 256 + wave * 64) << 3]);
    gload_lds16(&Bp[(n0 + row) * LDK + ktv + scol], &sB[(c * 256 + wave * 64) << 3]);
  }
}

__device__ __forceinline__ void load_frags(
    const __hip_bfloat16* sA, const __hip_bfloat16* sB,
    int wr, int wc, int r15, int khi, bf16x8 (&af)[4][2], bf16x8 (&bf)[4][2]) {
#pragma unroll
  for (int m = 0; m < 4; ++m)
#pragma unroll
    for (int kk = 0; kk < 2; ++kk) {
      const int row = wr * 64 + m * 16 + r15;
      const int slot = (kk * 4 + khi) ^ (row & 7);
      af[m][kk] = *reinterpret_cast<const bf16x8*>(&sA[row * 64 + slot * 8]);
    }
#pragma unroll
  for (int n = 0; n < 4; ++n)
#pragma unroll
    for (int kk = 0; kk < 2; ++kk) {
      const int row = wc * 64 + n * 16 + r15;
      const int slot = (kk * 4 + khi) ^ (row & 7);
      bf[n][kk] = *reinterpret_cast<const bf16x8*>(&sB[row * 64 + slot * 8]);
    }
}

__device__ __forceinline__ void do_mfma(
    const bf16x8 (&af)[4][2], const bf16x8 (&bf)[4][2], f32x4 (&acc)[4][4]) {
#pragma unroll
  for (int kk = 0; kk < 2; ++kk)
#pragma unroll
    for (int m = 0; m < 4; ++m)
#pragma unroll
      for (int n = 0; n < 4; ++n)
        acc[m][n] = __builtin_amdgcn_mfma_f32_16x16x32_bf16(
            af[m][kk], bf[n][kk], acc[m][n], 0, 0, 0);
}

// ---------------------------------------------------------------------------
// Kernel 1: psi MFMA GEMM (unchanged, proven).
// ---------------------------------------------------------------------------
__global__ __launch_bounds__(NT)
void psi_mfma(const __hip_bfloat16* __restrict__ wb,
              const __hip_bfloat16* __restrict__ DT,
              __hip_bfloat16* __restrict__ PT) {
  const int m0 = blockIdx.x * 128, n0 = blockIdx.y * 128;

  __shared__ __hip_bfloat16 sA[2][128 * 64];
  __shared__ __hip_bfloat16 sB[2][128 * 64];

  const int tid = threadIdx.x;
  const int lane = tid & 63, wave = tid >> 6;
  const int wr = wave & 1, wc = wave >> 1;
  const int r15 = lane & 15, khi = lane >> 4;

  f32x4 acc[4][4] = {};
  bf16x8 af[4][2], bf[4][2];

  stage_tile(wb, DT, 512, 0, m0, n0, tid, wave, sA[0], sB[0]);
  __syncthreads();
  int cur = 0;
  for (int t = 0; t < 8; ++t) {
    if (t + 1 < 8)
      stage_tile(wb, DT, 512, (t + 1) << 6, m0, n0, tid, wave, sA[cur ^ 1], sB[cur ^ 1]);
    load_frags(sA[cur], sB[cur], wr, wc, r15, khi, af, bf);
    do_mfma(af, bf, acc);
    if (t + 1 < 8) { __syncthreads(); cur ^= 1; }
  }

#pragma unroll
  for (int n = 0; n < 4; ++n) {
    const int s = n0 + wc * 64 + n * 16 + r15;
    if (s >= 286) continue;
    int off, d;
    decode_s(s, off, d);
    const int rel = s - off;
    const int u = rel / d, v = rel - u * d;
    const float scale = 1.0f / (256.0f * sqrtf((float)d));
    __hip_bfloat16* Pl = PT + off * 16384;
    const int Kd = 128 * d;
#pragma unroll
    for (int m = 0; m < 4; ++m)
#pragma unroll
      for (int j = 0; j < 4; ++j) {
        const int row = m0 + wr * 64 + m * 16 + khi * 4 + j;
        const int x = row >> 7, y = row & 127;
        Pl[(y * d + v) * Kd + (x * d + u)] = __float2bfloat16(acc[m][n][j] * scale);
      }
  }
}

// ---------------------------------------------------------------------------
// Kernel 2: main GEMM (passing kernel) — R8 dbuf structure + template-D.
// ---------------------------------------------------------------------------
template<int D, int OFF>
__device__ __forceinline__ void tile_body(
    const __hip_bfloat16* __restrict__ Aall,
    const __hip_bfloat16* __restrict__ PTall,
    float* __restrict__ out, int bx,
    __hip_bfloat16 (*sA)[128 * 64], __hip_bfloat16 (*sB)[128 * 64]) {
  const int tid = threadIdx.x;
  const int lane = tid & 63, wave = tid >> 6;
  const int wr = wave & 1, wc = wave >> 1;
  const int r15 = lane & 15, khi = lane >> 4;

  constexpr int Kn = 128 * D;
  constexpr int nk = 2 * D;
  const int bm = bx % (4 * D);
  const int bn = bx / (4 * D);
  const __hip_bfloat16* A  = Aall  + 65536 * OFF;
  const __hip_bfloat16* BT = PTall + 16384 * OFF;
  const int m0 = bm * 128, n0 = bn * 128;

  f32x4 acc[4][4] = {};
  bf16x8 af[4][2], bf[4][2];

  stage_tile(A, BT, Kn, 0, m0, n0, tid, wave, sA[0], sB[0]);
  __syncthreads();
  int cur = 0;
  for (int t = 0; t < nk; ++t) {
    if (t + 1 < nk)
      stage_tile(A, BT, Kn, (t + 1) << 6, m0, n0, tid, wave, sA[cur ^ 1], sB[cur ^ 1]);
    load_frags(sA[cur], sB[cur], wr, wc, r15, khi, af, bf);
    do_mfma(af, bf, acc);
    if (t + 1 < nk) { __syncthreads(); cur ^= 1; }
  }

  int yo4[4], v4[4];
#pragma unroll
  for (int n = 0; n < 4; ++n) {
    const int col = n0 + wc * 64 + n * 16 + r15;
    yo4[n] = col / D;
    v4[n] = col - yo4[n] * D;
  }
#pragma unroll
  for (int m = 0; m < 4; ++m)
#pragma unroll
    for (int j = 0; j < 4; ++j) {
      const int row = m0 + wr * 64 + m * 16 + khi * 4 + j;
      const int bb = row / D, i = row - bb * D;
      float* orow = out + (size_t)bb * 36608 + OFF + i;
#pragma unroll
      for (int n = 0; n < 4; ++n)
        orow[yo4[n] * 286 + v4[n] * D] = acc[m][n][j];
    }
}

__global__ __launch_bounds__(NT)
void main_gemm(const __hip_bfloat16* __restrict__ Aall,
               const __hip_bfloat16* __restrict__ PTall,
               float* __restrict__ out) {
  __shared__ __hip_bfloat16 sA[2][128 * 64];
  __shared__ __hip_bfloat16 sB[2][128 * 64];
  const int bx = blockIdx.x;
  if (bx < 484)       tile_body<11, 165>(Aall, PTall, out, bx, sA, sB);
  else if (bx < 808)  tile_body<9, 84>(Aall, PTall, out, bx - 484, sA, sB);
  else if (bx < 1004) tile_body<7, 35>(Aall, PTall, out, bx - 808, sA, sB);
  else if (bx < 1104) tile_body<5, 10>(Aall, PTall, out, bx - 1004, sA, sB);
  else if (bx < 1140) tile_body<3, 1>(Aall, PTall, out, bx - 1104, sA, sB);
  else                tile_body<1, 0>(Aall, PTall, out, bx - 1140, sA, sB);
}

// ---------------------------------------------------------------------------
// ABLATION A: staging skeleton only (same gload_lds cadence + barriers,
// no ds_read/MFMA). Writes one float/thread to dead scratch (wb region).
// ---------------------------------------------------------------------------
template<int D, int OFF>
__device__ __forceinline__ void ab_stage_body(
    const __hip_bfloat16* __restrict__ Aall,
    const __hip_bfloat16* __restrict__ PTall,
    float* __restrict__ scr, int bx,
    __hip_bfloat16 (*sA)[128 * 64], __hip_bfloat16 (*sB)[128 * 64]) {
  const int tid = threadIdx.x;
  const int wave = tid >> 6;
  constexpr int Kn = 128 * D;
  constexpr int nk = 2 * D;
  const int bm = bx % (4 * D);
  const int bn = bx / (4 * D);
  const __hip_bfloat16* A  = Aall  + 65536 * OFF;
  const __hip_bfloat16* BT = PTall + 16384 * OFF;
  const int m0 = bm * 128, n0 = bn * 128;

  stage_tile(A, BT, Kn, 0, m0, n0, tid, wave, sA[0], sB[0]);
  __syncthreads();
  int cur = 0;
  for (int t = 0; t < nk; ++t) {
    if (t + 1 < nk) {
      stage_tile(A, BT, Kn, (t + 1) << 6, m0, n0, tid, wave, sA[cur ^ 1], sB[cur ^ 1]);
      __syncthreads();
      cur ^= 1;
    }
  }
  __syncthreads();
  // keep LDS live
  const float* fa = reinterpret_cast<const float*>(sA[cur]);
  const float* fb = reinterpret_cast<const float*>(sB[cur]);
  scr[blockIdx.x * NT + tid] = fa[tid] + fb[tid];
}

__global__ __launch_bounds__(NT)
void ab_stage(const __hip_bfloat16* __restrict__ Aall,
              const __hip_bfloat16* __restrict__ PTall,
              float* __restrict__ scr) {
  __shared__ __hip_bfloat16 sA[2][128 * 64];
  __shared__ __hip_bfloat16 sB[2][128 * 64];
  const int bx = blockIdx.x;
  if (bx < 484)       ab_stage_body<11, 165>(Aall, PTall, scr, bx, sA, sB);
  else if (bx < 808)  ab_stage_body<9, 84>(Aall, PTall, scr, bx - 484, sA, sB);
  else if (bx < 1004) ab_stage_body<7, 35>(Aall, PTall, scr, bx - 808, sA, sB);
  else if (bx < 1104) ab_stage_body<5, 10>(Aall, PTall, scr, bx - 1004, sA, sB);
  else if (bx < 1140) ab_stage_body<3, 1>(Aall, PTall, scr, bx - 1104, sA, sB);
  else                ab_stage_body<1, 0>(Aall, PTall, scr, bx - 1140, sA, sB);
}

// ---------------------------------------------------------------------------
// ABLATION B: compute skeleton only (ds_read frags + MFMA + barriers on
// uninitialized LDS; zero global loads). acc kept live via scratch store.
// ---------------------------------------------------------------------------
template<int D>
__device__ __forceinline__ void ab_comp_body(
    float* __restrict__ scr, int bx,
    __hip_bfloat16 (*sA)[128 * 64], __hip_bfloat16 (*sB)[128 * 64]) {
  const int tid = threadIdx.x;
  const int lane = tid & 63, wave = tid >> 6;
  const int wr = wave & 1, wc = wave >> 1;
  const int r15 = lane & 15, khi = lane >> 4;
  constexpr int nk = 2 * D;

  f32x4 acc[4][4] = {};
  bf16x8 af[4][2], bf[4][2];

  __syncthreads();
  for (int t = 0; t < nk; ++t) {
    load_frags(sA[t & 1], sB[t & 1], wr, wc, r15, khi, af, bf);
    do_mfma(af, bf, acc);
    if (t + 1 < nk) __syncthreads();
  }
  f32x4 s = acc[0][0];
#pragma unroll
  for (int m = 0; m < 4; ++m)
#pragma unroll
    for (int n = 0; n < 4; ++n)
      if (m + n) s += acc[m][n];
  *reinterpret_cast<f32x4*>(&scr[(blockIdx.x * NT + tid) * 4]) = s;
}

__global__ __launch_bounds__(NT)
void ab_comp(float* __restrict__ scr) {
  __shared__ __hip_bfloat16 sA[2][128 * 64];
  __shared__ __hip_bfloat16 sB[2][128 * 64];
  const int bx = blockIdx.x;
  if (bx < 484)       ab_comp_body<11>(scr, bx, sA, sB);
  else if (bx < 808)  ab_comp_body<9>(scr, bx - 484, sA, sB);
  else if (bx < 1004) ab_comp_body<7>(scr, bx - 808, sA, sB);
  else if (bx < 1104) ab_comp_body<5>(scr, bx - 1004, sA, sB);
  else if (bx < 1140) ab_comp_body<3>(scr, bx - 1104, sA, sB);
  else                ab_comp_body<1>(scr, bx - 1140, sA, sB);
}

// ---------------------------------------------------------------------------
extern "C" void kernel_launch(void* const* d_in, const int* in_sizes, int n_in,
                              void* d_out, int out_size, void* d_ws, size_t ws_size,
                              hipStream_t stream) {
  const float* x  = (const float*)d_in[0];  // (512,128,286)
  const float* w  = (const float*)d_in[1];  // (128,128,512)
  const float* Dm = (const float*)d_in[2];  // (512,286)
  float* out = (float*)d_out;               // (512,128,286)

  // Workspace (bf16 elems): PT 16384*286 ; A 65536*286 ; wb 16384*512 ;
  // DT 384*512.  wb is DEAD after psi_mfma -> reused as ablation scratch.
  __hip_bfloat16* PT = (__hip_bfloat16*)d_ws;
  __hip_bfloat16* A  = PT + 16384 * 286;
  __hip_bfloat16* wb = A + 65536 * 286;
  __hip_bfloat16* DT = wb + 16384 * 512;
  float* scr = (float*)wb;                  // 8.4M floats available

  prep_all<<<dim3(7936), dim3(NT), 0, stream>>>(w, Dm, x, wb, DT, A);
  psi_mfma<<<dim3(128, 3), dim3(NT), 0, stream>>>(wb, DT, PT);
  main_gemm<<<dim3(1144), dim3(NT), 0, stream>>>(A, PT, out);
  // --- ablation dispatches (write only to dead scratch; per-dispatch rocprof)
  ab_stage<<<dim3(1144), dim3(NT), 0, stream>>>(A, PT, scr);
  ab_comp<<<dim3(1144), dim3(NT), 0, stream>>>(scr + 2097152);
}

// Round 17
// 261.761 us; speedup vs baseline: 1.0518x; 1.0518x over previous
//
#include <hip/hip_runtime.h>
#include <hip/hip_bf16.h>

// SO3Conv restructured (see R7-R16 journal):
//   PT_l[(yo,v)][(x,u)] = psi_l scaled, bf16 ; A_l[(b,i)][(x,u)] = x, bf16
//   Y_l = A_l . PT_l^T  via mfma_f32_16x16x32_bf16
// l=0..5, d=2l+1, off_l = {0,1,10,35,84,165}.
// R17: R8-proven dbuf main_gemm + template-D epilogue, launch_bounds(256,4)
// VGPR cap (R16 showed 132-VGPR cliff = 175us), bijective XCD swizzle
// (1144%8==0): XCD k gets contiguous tiles [143k,143k+143) for L2 locality.

#define NT 256
typedef __bf16 bf16x8 __attribute__((ext_vector_type(8)));
typedef float f32x4 __attribute__((ext_vector_type(4)));
typedef unsigned int u32;

__device__ __forceinline__ void gload_lds16(const void* g, void* l) {
  __builtin_amdgcn_global_load_lds(
      (const __attribute__((address_space(1))) u32*)g,
      (__attribute__((address_space(3))) u32*)l, 16, 0, 0);
}

__device__ __forceinline__ void decode_s(int s, int& off, int& d) {
  if (s >= 165)      { off = 165; d = 11; }
  else if (s >= 84)  { off = 84;  d = 9; }
  else if (s >= 35)  { off = 35;  d = 7; }
  else if (s >= 10)  { off = 10;  d = 5; }
  else if (s >= 1)   { off = 1;   d = 3; }
  else               { off = 0;   d = 1; }
}

// ---------------------------------------------------------------------------
// Kernel 0: prep_all (7936 blocks): wb=bf16(w); DT=bf16(D^T) padded; build_A.
// ---------------------------------------------------------------------------
template<int D, int OFF>
__device__ __forceinline__ void build_one(const float* __restrict__ X,
                                          __hip_bfloat16* __restrict__ A,
                                          int b, __hip_bfloat16* sm) {
  const float* src = X + (size_t)b * (128 * 286) + OFF;
  for (int e = threadIdx.x; e < 128 * D * D; e += NT) {
    const int x = e / (D * D), r = e - x * (D * D);
    sm[e] = __float2bfloat16(src[x * 286 + r]);
  }
  __syncthreads();
  __hip_bfloat16* dst = A + (size_t)65536 * OFF + (size_t)b * (D * 128 * D);
  for (int o = threadIdx.x; o < D * 128 * D; o += NT) {
    const int i = o / (128 * D);
    const int rem = o - i * (128 * D);
    const int x = rem / D, u = rem - x * D;
    dst[o] = sm[x * D * D + u * D + i];
  }
}

__global__ __launch_bounds__(NT)
void prep_all(const float* __restrict__ w, const float* __restrict__ Dm,
              const float* __restrict__ X,
              __hip_bfloat16* __restrict__ wb, __hip_bfloat16* __restrict__ DT,
              __hip_bfloat16* __restrict__ A) {
  __shared__ __hip_bfloat16 sm[128 * 121];
  const int bx = blockIdx.x;
  if (bx < 4096) {
    const int t = bx * NT + threadIdx.x;
    const float4 a = reinterpret_cast<const float4*>(w)[t * 2];
    const float4 b = reinterpret_cast<const float4*>(w)[t * 2 + 1];
    __hip_bfloat16 v[8];
    v[0] = __float2bfloat16(a.x); v[1] = __float2bfloat16(a.y);
    v[2] = __float2bfloat16(a.z); v[3] = __float2bfloat16(a.w);
    v[4] = __float2bfloat16(b.x); v[5] = __float2bfloat16(b.y);
    v[6] = __float2bfloat16(b.z); v[7] = __float2bfloat16(b.w);
    *reinterpret_cast<bf16x8*>(&wb[t * 8]) = *reinterpret_cast<bf16x8*>(v);
  } else if (bx < 4864) {
    const int e = (bx - 4096) * NT + threadIdx.x;  // 196,608 = 384*512
    const int s = e >> 9, g = e & 511;
    DT[e] = (s < 286) ? __float2bfloat16(Dm[g * 286 + s]) : __float2bfloat16(0.0f);
  } else {
    const int b2 = bx - 4864;
    if (b2 < 512)       build_one<11, 165>(X, A, b2, sm);
    else if (b2 < 1024) build_one<9, 84>(X, A, b2 - 512, sm);
    else if (b2 < 1536) build_one<7, 35>(X, A, b2 - 1024, sm);
    else if (b2 < 2048) build_one<5, 10>(X, A, b2 - 1536, sm);
    else if (b2 < 2560) build_one<3, 1>(X, A, b2 - 2048, sm);
    else                build_one<1, 0>(X, A, b2 - 2560, sm);
  }
}

// ---------------------------------------------------------------------------
// Shared helpers (proven R7/R8 structure).
// ---------------------------------------------------------------------------
__device__ __forceinline__ void stage_tile(
    const __hip_bfloat16* __restrict__ Ap, const __hip_bfloat16* __restrict__ Bp,
    int LDK, int ktv, int m0, int n0, int tid, int wave,
    __hip_bfloat16* sA, __hip_bfloat16* sB) {
#pragma unroll
  for (int c = 0; c < 4; ++c) {
    const int q = c * 256 + tid;
    const int row = q >> 3, slot = q & 7;
    const int scol = ((slot ^ (row & 7)) << 3);
    gload_lds16(&Ap[(m0 + row) * LDK + ktv + scol], &sA[(c * 256 + wave * 64) << 3]);
    gload_lds16(&Bp[(n0 + row) * LDK + ktv + scol], &sB[(c * 256 + wave * 64) << 3]);
  }
}

__device__ __forceinline__ void load_frags(
    const __hip_bfloat16* sA, const __hip_bfloat16* sB,
    int wr, int wc, int r15, int khi, bf16x8 (&af)[4][2], bf16x8 (&bf)[4][2]) {
#pragma unroll
  for (int m = 0; m < 4; ++m)
#pragma unroll
    for (int kk = 0; kk < 2; ++kk) {
      const int row = wr * 64 + m * 16 + r15;
      const int slot = (kk * 4 + khi) ^ (row & 7);
      af[m][kk] = *reinterpret_cast<const bf16x8*>(&sA[row * 64 + slot * 8]);
    }
#pragma unroll
  for (int n = 0; n < 4; ++n)
#pragma unroll
    for (int kk = 0; kk < 2; ++kk) {
      const int row = wc * 64 + n * 16 + r15;
      const int slot = (kk * 4 + khi) ^ (row & 7);
      bf[n][kk] = *reinterpret_cast<const bf16x8*>(&sB[row * 64 + slot * 8]);
    }
}

__device__ __forceinline__ void do_mfma(
    const bf16x8 (&af)[4][2], const bf16x8 (&bf)[4][2], f32x4 (&acc)[4][4]) {
#pragma unroll
  for (int kk = 0; kk < 2; ++kk)
#pragma unroll
    for (int m = 0; m < 4; ++m)
#pragma unroll
      for (int n = 0; n < 4; ++n)
        acc[m][n] = __builtin_amdgcn_mfma_f32_16x16x32_bf16(
            af[m][kk], bf[n][kk], acc[m][n], 0, 0, 0);
}

// ---------------------------------------------------------------------------
// Kernel 1: psi MFMA GEMM (unchanged, proven).
// ---------------------------------------------------------------------------
__global__ __launch_bounds__(NT)
void psi_mfma(const __hip_bfloat16* __restrict__ wb,
              const __hip_bfloat16* __restrict__ DT,
              __hip_bfloat16* __restrict__ PT) {
  const int m0 = blockIdx.x * 128, n0 = blockIdx.y * 128;

  __shared__ __hip_bfloat16 sA[2][128 * 64];
  __shared__ __hip_bfloat16 sB[2][128 * 64];

  const int tid = threadIdx.x;
  const int lane = tid & 63, wave = tid >> 6;
  const int wr = wave & 1, wc = wave >> 1;
  const int r15 = lane & 15, khi = lane >> 4;

  f32x4 acc[4][4] = {};
  bf16x8 af[4][2], bf[4][2];

  stage_tile(wb, DT, 512, 0, m0, n0, tid, wave, sA[0], sB[0]);
  __syncthreads();
  int cur = 0;
  for (int t = 0; t < 8; ++t) {
    if (t + 1 < 8)
      stage_tile(wb, DT, 512, (t + 1) << 6, m0, n0, tid, wave, sA[cur ^ 1], sB[cur ^ 1]);
    load_frags(sA[cur], sB[cur], wr, wc, r15, khi, af, bf);
    do_mfma(af, bf, acc);
    if (t + 1 < 8) { __syncthreads(); cur ^= 1; }
  }

#pragma unroll
  for (int n = 0; n < 4; ++n) {
    const int s = n0 + wc * 64 + n * 16 + r15;
    if (s >= 286) continue;
    int off, d;
    decode_s(s, off, d);
    const int rel = s - off;
    const int u = rel / d, v = rel - u * d;
    const float scale = 1.0f / (256.0f * sqrtf((float)d));
    __hip_bfloat16* Pl = PT + off * 16384;
    const int Kd = 128 * d;
#pragma unroll
    for (int m = 0; m < 4; ++m)
#pragma unroll
      for (int j = 0; j < 4; ++j) {
        const int row = m0 + wr * 64 + m * 16 + khi * 4 + j;
        const int x = row >> 7, y = row & 127;
        Pl[(y * d + v) * Kd + (x * d + u)] = __float2bfloat16(acc[m][n][j] * scale);
      }
  }
}

// ---------------------------------------------------------------------------
// Kernel 2: main GEMM — R8 dbuf structure + template-D epilogue +
// bijective XCD swizzle + VGPR cap (launch_bounds min 4 waves/EU).
// ---------------------------------------------------------------------------
template<int D, int OFF>
__device__ __forceinline__ void tile_body(
    const __hip_bfloat16* __restrict__ Aall,
    const __hip_bfloat16* __restrict__ PTall,
    float* __restrict__ out, int bx,
    __hip_bfloat16 (*sA)[128 * 64], __hip_bfloat16 (*sB)[128 * 64]) {
  const int tid = threadIdx.x;
  const int lane = tid & 63, wave = tid >> 6;
  const int wr = wave & 1, wc = wave >> 1;
  const int r15 = lane & 15, khi = lane >> 4;

  constexpr int Kn = 128 * D;
  constexpr int nk = 2 * D;
  const int bm = bx % (4 * D);       // bm fastest: consecutive tiles share B
  const int bn = bx / (4 * D);
  const __hip_bfloat16* A  = Aall  + 65536 * OFF;
  const __hip_bfloat16* BT = PTall + 16384 * OFF;
  const int m0 = bm * 128, n0 = bn * 128;

  f32x4 acc[4][4] = {};
  bf16x8 af[4][2], bf[4][2];

  stage_tile(A, BT, Kn, 0, m0, n0, tid, wave, sA[0], sB[0]);
  __syncthreads();
  int cur = 0;
  for (int t = 0; t < nk; ++t) {
    if (t + 1 < nk)
      stage_tile(A, BT, Kn, (t + 1) << 6, m0, n0, tid, wave, sA[cur ^ 1], sB[cur ^ 1]);
    load_frags(sA[cur], sB[cur], wr, wc, r15, khi, af, bf);
    do_mfma(af, bf, acc);
    if (t + 1 < nk) { __syncthreads(); cur ^= 1; }
  }

  int yo4[4], v4[4];
#pragma unroll
  for (int n = 0; n < 4; ++n) {
    const int col = n0 + wc * 64 + n * 16 + r15;
    yo4[n] = col / D;
    v4[n] = col - yo4[n] * D;
  }
#pragma unroll
  for (int m = 0; m < 4; ++m)
#pragma unroll
    for (int j = 0; j < 4; ++j) {
      const int row = m0 + wr * 64 + m * 16 + khi * 4 + j;
      const int bb = row / D, i = row - bb * D;
      float* orow = out + (size_t)bb * 36608 + OFF + i;
#pragma unroll
      for (int n = 0; n < 4; ++n)
        orow[yo4[n] * 286 + v4[n] * D] = acc[m][n][j];
    }
}

__global__ __launch_bounds__(NT, 4)
void main_gemm(const __hip_bfloat16* __restrict__ Aall,
               const __hip_bfloat16* __restrict__ PTall,
               float* __restrict__ out) {
  __shared__ __hip_bfloat16 sA[2][128 * 64];
  __shared__ __hip_bfloat16 sB[2][128 * 64];
  // Bijective XCD swizzle (1144 = 8 * 143): hardware round-robins blockIdx
  // across XCDs, so XCD k receives raw indices {k, k+8, ...} -> contiguous
  // tile range [143k, 143k+143). Consecutive tiles share B-panels (bm-fastest)
  // -> staging hits the local L2 instead of remote/HBM.
  const int raw = blockIdx.x;
  const int bx = (raw & 7) * 143 + (raw >> 3);
  if (bx < 484)       tile_body<11, 165>(Aall, PTall, out, bx, sA, sB);
  else if (bx < 808)  tile_body<9, 84>(Aall, PTall, out, bx - 484, sA, sB);
  else if (bx < 1004) tile_body<7, 35>(Aall, PTall, out, bx - 808, sA, sB);
  else if (bx < 1104) tile_body<5, 10>(Aall, PTall, out, bx - 1004, sA, sB);
  else if (bx < 1140) tile_body<3, 1>(Aall, PTall, out, bx - 1104, sA, sB);
  else                tile_body<1, 0>(Aall, PTall, out, bx - 1140, sA, sB);
}

// ---------------------------------------------------------------------------
extern "C" void kernel_launch(void* const* d_in, const int* in_sizes, int n_in,
                              void* d_out, int out_size, void* d_ws, size_t ws_size,
                              hipStream_t stream) {
  const float* x  = (const float*)d_in[0];  // (512,128,286)
  const float* w  = (const float*)d_in[1];  // (128,128,512)
  const float* Dm = (const float*)d_in[2];  // (512,286)
  float* out = (float*)d_out;               // (512,128,286)

  // Workspace (bf16 elems): PT 16384*286 ; A 65536*286 ; wb 16384*512 ;
  // DT 384*512.
  __hip_bfloat16* PT = (__hip_bfloat16*)d_ws;
  __hip_bfloat16* A  = PT + 16384 * 286;
  __hip_bfloat16* wb = A + 65536 * 286;
  __hip_bfloat16* DT = wb + 16384 * 512;

  prep_all<<<dim3(7936), dim3(NT), 0, stream>>>(w, Dm, x, wb, DT, A);
  psi_mfma<<<dim3(128, 3), dim3(NT), 0, stream>>>(wb, DT, PT);
  main_gemm<<<dim3(1144), dim3(NT), 0, stream>>>(A, PT, out);
}

// Round 18
// 162.732 us; speedup vs baseline: 1.6919x; 1.6085x over previous
//
#include <hip/hip_runtime.h>
#include <hip/hip_bf16.h>

// SO3Conv restructured (journal R7-R17):
//   PT_l[(yo,v)][(x,u)] = psi_l scaled, bf16 ; A_l[(b,i)][(x,u)] = x, bf16
//   Y_l = A_l . PT_l^T  via mfma_f32_16x16x32_bf16
// l=0..5, d=2l+1, off_l = {0,1,10,35,84,165}.
// R18 = measured-best recombination: R8's exact main_gemm (runtime-d, VGPR 88,
// 107us) + R13's merged prep_all + proven psi_mfma. No swizzle (R17: -28us),
// no templates in main (R16/R17: VGPR 132 cliff), no launch_bounds cap.

#define NT 256
typedef __bf16 bf16x8 __attribute__((ext_vector_type(8)));
typedef float f32x4 __attribute__((ext_vector_type(4)));
typedef unsigned int u32;

__device__ __forceinline__ void gload_lds16(const void* g, void* l) {
  __builtin_amdgcn_global_load_lds(
      (const __attribute__((address_space(1))) u32*)g,
      (__attribute__((address_space(3))) u32*)l, 16, 0, 0);
}

__device__ __forceinline__ void decode_s(int s, int& off, int& d) {
  if (s >= 165)      { off = 165; d = 11; }
  else if (s >= 84)  { off = 84;  d = 9; }
  else if (s >= 35)  { off = 35;  d = 7; }
  else if (s >= 10)  { off = 10;  d = 5; }
  else if (s >= 1)   { off = 1;   d = 3; }
  else               { off = 0;   d = 1; }
}

// ---------------------------------------------------------------------------
// Kernel 0: prep_all (7936 blocks): wb=bf16(w); DT=bf16(D^T) padded; build_A.
// ---------------------------------------------------------------------------
template<int D, int OFF>
__device__ __forceinline__ void build_one(const float* __restrict__ X,
                                          __hip_bfloat16* __restrict__ A,
                                          int b, __hip_bfloat16* sm) {
  const float* src = X + (size_t)b * (128 * 286) + OFF;
  for (int e = threadIdx.x; e < 128 * D * D; e += NT) {
    const int x = e / (D * D), r = e - x * (D * D);
    sm[e] = __float2bfloat16(src[x * 286 + r]);
  }
  __syncthreads();
  __hip_bfloat16* dst = A + (size_t)65536 * OFF + (size_t)b * (D * 128 * D);
  for (int o = threadIdx.x; o < D * 128 * D; o += NT) {
    const int i = o / (128 * D);
    const int rem = o - i * (128 * D);
    const int x = rem / D, u = rem - x * D;
    dst[o] = sm[x * D * D + u * D + i];
  }
}

__global__ __launch_bounds__(NT)
void prep_all(const float* __restrict__ w, const float* __restrict__ Dm,
              const float* __restrict__ X,
              __hip_bfloat16* __restrict__ wb, __hip_bfloat16* __restrict__ DT,
              __hip_bfloat16* __restrict__ A) {
  __shared__ __hip_bfloat16 sm[128 * 121];
  const int bx = blockIdx.x;
  if (bx < 4096) {
    const int t = bx * NT + threadIdx.x;
    const float4 a = reinterpret_cast<const float4*>(w)[t * 2];
    const float4 b = reinterpret_cast<const float4*>(w)[t * 2 + 1];
    __hip_bfloat16 v[8];
    v[0] = __float2bfloat16(a.x); v[1] = __float2bfloat16(a.y);
    v[2] = __float2bfloat16(a.z); v[3] = __float2bfloat16(a.w);
    v[4] = __float2bfloat16(b.x); v[5] = __float2bfloat16(b.y);
    v[6] = __float2bfloat16(b.z); v[7] = __float2bfloat16(b.w);
    *reinterpret_cast<bf16x8*>(&wb[t * 8]) = *reinterpret_cast<bf16x8*>(v);
  } else if (bx < 4864) {
    const int e = (bx - 4096) * NT + threadIdx.x;  // 196,608 = 384*512
    const int s = e >> 9, g = e & 511;
    DT[e] = (s < 286) ? __float2bfloat16(Dm[g * 286 + s]) : __float2bfloat16(0.0f);
  } else {
    const int b2 = bx - 4864;
    if (b2 < 512)       build_one<11, 165>(X, A, b2, sm);
    else if (b2 < 1024) build_one<9, 84>(X, A, b2 - 512, sm);
    else if (b2 < 1536) build_one<7, 35>(X, A, b2 - 1024, sm);
    else if (b2 < 2048) build_one<5, 10>(X, A, b2 - 1536, sm);
    else if (b2 < 2560) build_one<3, 1>(X, A, b2 - 2048, sm);
    else                build_one<1, 0>(X, A, b2 - 2560, sm);
  }
}

// ---------------------------------------------------------------------------
// Shared helpers (proven R7/R8 structure).
// ---------------------------------------------------------------------------
__device__ __forceinline__ void stage_tile(
    const __hip_bfloat16* __restrict__ Ap, const __hip_bfloat16* __restrict__ Bp,
    int LDK, int ktv, int m0, int n0, int tid, int wave,
    __hip_bfloat16* sA, __hip_bfloat16* sB) {
#pragma unroll
  for (int c = 0; c < 4; ++c) {
    const int q = c * 256 + tid;
    const int row = q >> 3, slot = q & 7;
    const int scol = ((slot ^ (row & 7)) << 3);
    gload_lds16(&Ap[(m0 + row) * LDK + ktv + scol], &sA[(c * 256 + wave * 64) << 3]);
    gload_lds16(&Bp[(n0 + row) * LDK + ktv + scol], &sB[(c * 256 + wave * 64) << 3]);
  }
}

__device__ __forceinline__ void load_frags(
    const __hip_bfloat16* sA, const __hip_bfloat16* sB,
    int wr, int wc, int r15, int khi, bf16x8 (&af)[4][2], bf16x8 (&bf)[4][2]) {
#pragma unroll
  for (int m = 0; m < 4; ++m)
#pragma unroll
    for (int kk = 0; kk < 2; ++kk) {
      const int row = wr * 64 + m * 16 + r15;
      const int slot = (kk * 4 + khi) ^ (row & 7);
      af[m][kk] = *reinterpret_cast<const bf16x8*>(&sA[row * 64 + slot * 8]);
    }
#pragma unroll
  for (int n = 0; n < 4; ++n)
#pragma unroll
    for (int kk = 0; kk < 2; ++kk) {
      const int row = wc * 64 + n * 16 + r15;
      const int slot = (kk * 4 + khi) ^ (row & 7);
      bf[n][kk] = *reinterpret_cast<const bf16x8*>(&sB[row * 64 + slot * 8]);
    }
}

__device__ __forceinline__ void do_mfma(
    const bf16x8 (&af)[4][2], const bf16x8 (&bf)[4][2], f32x4 (&acc)[4][4]) {
#pragma unroll
  for (int kk = 0; kk < 2; ++kk)
#pragma unroll
    for (int m = 0; m < 4; ++m)
#pragma unroll
      for (int n = 0; n < 4; ++n)
        acc[m][n] = __builtin_amdgcn_mfma_f32_16x16x32_bf16(
            af[m][kk], bf[n][kk], acc[m][n], 0, 0, 0);
}

// ---------------------------------------------------------------------------
// Kernel 1: psi MFMA GEMM (unchanged, proven).
// ---------------------------------------------------------------------------
__global__ __launch_bounds__(NT)
void psi_mfma(const __hip_bfloat16* __restrict__ wb,
              const __hip_bfloat16* __restrict__ DT,
              __hip_bfloat16* __restrict__ PT) {
  const int m0 = blockIdx.x * 128, n0 = blockIdx.y * 128;

  __shared__ __hip_bfloat16 sA[2][128 * 64];
  __shared__ __hip_bfloat16 sB[2][128 * 64];

  const int tid = threadIdx.x;
  const int lane = tid & 63, wave = tid >> 6;
  const int wr = wave & 1, wc = wave >> 1;
  const int r15 = lane & 15, khi = lane >> 4;

  f32x4 acc[4][4] = {};
  bf16x8 af[4][2], bf[4][2];

  stage_tile(wb, DT, 512, 0, m0, n0, tid, wave, sA[0], sB[0]);
  __syncthreads();
  int cur = 0;
  for (int t = 0; t < 8; ++t) {
    if (t + 1 < 8)
      stage_tile(wb, DT, 512, (t + 1) << 6, m0, n0, tid, wave, sA[cur ^ 1], sB[cur ^ 1]);
    load_frags(sA[cur], sB[cur], wr, wc, r15, khi, af, bf);
    do_mfma(af, bf, acc);
    if (t + 1 < 8) { __syncthreads(); cur ^= 1; }
  }

#pragma unroll
  for (int n = 0; n < 4; ++n) {
    const int s = n0 + wc * 64 + n * 16 + r15;
    if (s >= 286) continue;
    int off, d;
    decode_s(s, off, d);
    const int rel = s - off;
    const int u = rel / d, v = rel - u * d;
    const float scale = 1.0f / (256.0f * sqrtf((float)d));
    __hip_bfloat16* Pl = PT + off * 16384;
    const int Kd = 128 * d;
#pragma unroll
    for (int m = 0; m < 4; ++m)
#pragma unroll
      for (int j = 0; j < 4; ++j) {
        const int row = m0 + wr * 64 + m * 16 + khi * 4 + j;
        const int x = row >> 7, y = row & 127;
        Pl[(y * d + v) * Kd + (x * d + u)] = __float2bfloat16(acc[m][n][j] * scale);
      }
  }
}

// ---------------------------------------------------------------------------
// Kernel 2: main GEMM — exact R8 structure (runtime-d, dbuf, VGPR-lean).
// 1144 blocks, longest degree first. No swizzle, no extra launch bounds.
// ---------------------------------------------------------------------------
__global__ __launch_bounds__(NT)
void main_gemm(const __hip_bfloat16* __restrict__ Aall,
               const __hip_bfloat16* __restrict__ PTall,
               float* __restrict__ out) {
  int bx = blockIdx.x;
  int off, d;
  if (bx < 484)       { off = 165; d = 11; }
  else if (bx < 808)  { off = 84;  d = 9;  bx -= 484; }
  else if (bx < 1004) { off = 35;  d = 7;  bx -= 808; }
  else if (bx < 1104) { off = 10;  d = 5;  bx -= 1004; }
  else if (bx < 1140) { off = 1;   d = 3;  bx -= 1104; }
  else                { off = 0;   d = 1;  bx -= 1140; }
  const int bm = bx % (4 * d);
  const int bn = bx / (4 * d);
  const int Kn = 128 * d;
  const __hip_bfloat16* A  = Aall  + 65536 * off;
  const __hip_bfloat16* BT = PTall + 16384 * off;
  const int m0 = bm * 128, n0 = bn * 128;

  __shared__ __hip_bfloat16 sA[2][128 * 64];
  __shared__ __hip_bfloat16 sB[2][128 * 64];

  const int tid = threadIdx.x;
  const int lane = tid & 63, wave = tid >> 6;
  const int wr = wave & 1, wc = wave >> 1;
  const int r15 = lane & 15, khi = lane >> 4;

  f32x4 acc[4][4] = {};
  bf16x8 af[4][2], bf[4][2];

  const int nk = Kn >> 6;
  stage_tile(A, BT, Kn, 0, m0, n0, tid, wave, sA[0], sB[0]);
  __syncthreads();
  int cur = 0;
  for (int t = 0; t < nk; ++t) {
    if (t + 1 < nk)
      stage_tile(A, BT, Kn, (t + 1) << 6, m0, n0, tid, wave, sA[cur ^ 1], sB[cur ^ 1]);
    load_frags(sA[cur], sB[cur], wr, wc, r15, khi, af, bf);
    do_mfma(af, bf, acc);
    if (t + 1 < nk) { __syncthreads(); cur ^= 1; }
  }

  // Epilogue: row m=(b,i), col n=(yo,v) -> out[b][yo][off + v*d + i]
  int yo4[4], v4[4];
#pragma unroll
  for (int n = 0; n < 4; ++n) {
    const int col = n0 + wc * 64 + n * 16 + r15;
    yo4[n] = col / d;
    v4[n] = col - yo4[n] * d;
  }
#pragma unroll
  for (int m = 0; m < 4; ++m)
#pragma unroll
    for (int j = 0; j < 4; ++j) {
      const int row = m0 + wr * 64 + m * 16 + khi * 4 + j;
      const int bb = row / d, i = row - bb * d;
      float* orow = out + (size_t)bb * 36608 + off + i;
#pragma unroll
      for (int n = 0; n < 4; ++n)
        orow[yo4[n] * 286 + v4[n] * d] = acc[m][n][j];
    }
}

// ---------------------------------------------------------------------------
extern "C" void kernel_launch(void* const* d_in, const int* in_sizes, int n_in,
                              void* d_out, int out_size, void* d_ws, size_t ws_size,
                              hipStream_t stream) {
  const float* x  = (const float*)d_in[0];  // (512,128,286)
  const float* w  = (const float*)d_in[1];  // (128,128,512)
  const float* Dm = (const float*)d_in[2];  // (512,286)
  float* out = (float*)d_out;               // (512,128,286)

  // Workspace (bf16 elems): PT 16384*286 ; A 65536*286 ; wb 16384*512 ;
  // DT 384*512.
  __hip_bfloat16* PT = (__hip_bfloat16*)d_ws;
  __hip_bfloat16* A  = PT + 16384 * 286;
  __hip_bfloat16* wb = A + 65536 * 286;
  __hip_bfloat16* DT = wb + 16384 * 512;

  prep_all<<<dim3(7936), dim3(NT), 0, stream>>>(w, Dm, x, wb, DT, A);
  psi_mfma<<<dim3(128, 3), dim3(NT), 0, stream>>>(wb, DT, PT);
  main_gemm<<<dim3(1144), dim3(NT), 0, stream>>>(A, PT, out);
}

// Round 19
// 161.065 us; speedup vs baseline: 1.7094x; 1.0103x over previous
//
#include <hip/hip_runtime.h>
#include <hip/hip_bf16.h>

// SO3Conv restructured (journal R7-R18):
//   PT_l[(yo,v)][(x,u)] = psi_l scaled, bf16 ; A_l[(b,i)][(x,u)] = x, bf16
//   Y_l = A_l . PT_l^T  via mfma_f32_16x16x32_bf16
// l=0..5, d=2l+1, off_l = {0,1,10,35,84,165}.
// R19 = R18 verbatim (measured best: 162.7us total; main 108.3us/VGPR 88/
// FETCH 80MB). 12 structural variants measured; this is the 2-phase family
// optimum. prep_all is HBM-roofline-bound (164MB -> 26us). Further gains
// require the m201 8-phase schedule (exact vmcnt/chunk discipline not
// reconstructible here without race risk).

#define NT 256
typedef __bf16 bf16x8 __attribute__((ext_vector_type(8)));
typedef float f32x4 __attribute__((ext_vector_type(4)));
typedef unsigned int u32;

__device__ __forceinline__ void gload_lds16(const void* g, void* l) {
  __builtin_amdgcn_global_load_lds(
      (const __attribute__((address_space(1))) u32*)g,
      (__attribute__((address_space(3))) u32*)l, 16, 0, 0);
}

__device__ __forceinline__ void decode_s(int s, int& off, int& d) {
  if (s >= 165)      { off = 165; d = 11; }
  else if (s >= 84)  { off = 84;  d = 9; }
  else if (s >= 35)  { off = 35;  d = 7; }
  else if (s >= 10)  { off = 10;  d = 5; }
  else if (s >= 1)   { off = 1;   d = 3; }
  else               { off = 0;   d = 1; }
}

// ---------------------------------------------------------------------------
// Kernel 0: prep_all (7936 blocks): wb=bf16(w); DT=bf16(D^T) padded; build_A.
// ---------------------------------------------------------------------------
template<int D, int OFF>
__device__ __forceinline__ void build_one(const float* __restrict__ X,
                                          __hip_bfloat16* __restrict__ A,
                                          int b, __hip_bfloat16* sm) {
  const float* src = X + (size_t)b * (128 * 286) + OFF;
  for (int e = threadIdx.x; e < 128 * D * D; e += NT) {
    const int x = e / (D * D), r = e - x * (D * D);
    sm[e] = __float2bfloat16(src[x * 286 + r]);
  }
  __syncthreads();
  __hip_bfloat16* dst = A + (size_t)65536 * OFF + (size_t)b * (D * 128 * D);
  for (int o = threadIdx.x; o < D * 128 * D; o += NT) {
    const int i = o / (128 * D);
    const int rem = o - i * (128 * D);
    const int x = rem / D, u = rem - x * D;
    dst[o] = sm[x * D * D + u * D + i];
  }
}

__global__ __launch_bounds__(NT)
void prep_all(const float* __restrict__ w, const float* __restrict__ Dm,
              const float* __restrict__ X,
              __hip_bfloat16* __restrict__ wb, __hip_bfloat16* __restrict__ DT,
              __hip_bfloat16* __restrict__ A) {
  __shared__ __hip_bfloat16 sm[128 * 121];
  const int bx = blockIdx.x;
  if (bx < 4096) {
    const int t = bx * NT + threadIdx.x;
    const float4 a = reinterpret_cast<const float4*>(w)[t * 2];
    const float4 b = reinterpret_cast<const float4*>(w)[t * 2 + 1];
    __hip_bfloat16 v[8];
    v[0] = __float2bfloat16(a.x); v[1] = __float2bfloat16(a.y);
    v[2] = __float2bfloat16(a.z); v[3] = __float2bfloat16(a.w);
    v[4] = __float2bfloat16(b.x); v[5] = __float2bfloat16(b.y);
    v[6] = __float2bfloat16(b.z); v[7] = __float2bfloat16(b.w);
    *reinterpret_cast<bf16x8*>(&wb[t * 8]) = *reinterpret_cast<bf16x8*>(v);
  } else if (bx < 4864) {
    const int e = (bx - 4096) * NT + threadIdx.x;  // 196,608 = 384*512
    const int s = e >> 9, g = e & 511;
    DT[e] = (s < 286) ? __float2bfloat16(Dm[g * 286 + s]) : __float2bfloat16(0.0f);
  } else {
    const int b2 = bx - 4864;
    if (b2 < 512)       build_one<11, 165>(X, A, b2, sm);
    else if (b2 < 1024) build_one<9, 84>(X, A, b2 - 512, sm);
    else if (b2 < 1536) build_one<7, 35>(X, A, b2 - 1024, sm);
    else if (b2 < 2048) build_one<5, 10>(X, A, b2 - 1536, sm);
    else if (b2 < 2560) build_one<3, 1>(X, A, b2 - 2048, sm);
    else                build_one<1, 0>(X, A, b2 - 2560, sm);
  }
}

// ---------------------------------------------------------------------------
// Shared helpers (proven R7/R8 structure).
// ---------------------------------------------------------------------------
__device__ __forceinline__ void stage_tile(
    const __hip_bfloat16* __restrict__ Ap, const __hip_bfloat16* __restrict__ Bp,
    int LDK, int ktv, int m0, int n0, int tid, int wave,
    __hip_bfloat16* sA, __hip_bfloat16* sB) {
#pragma unroll
  for (int c = 0; c < 4; ++c) {
    const int q = c * 256 + tid;
    const int row = q >> 3, slot = q & 7;
    const int scol = ((slot ^ (row & 7)) << 3);
    gload_lds16(&Ap[(m0 + row) * LDK + ktv + scol], &sA[(c * 256 + wave * 64) << 3]);
    gload_lds16(&Bp[(n0 + row) * LDK + ktv + scol], &sB[(c * 256 + wave * 64) << 3]);
  }
}

__device__ __forceinline__ void load_frags(
    const __hip_bfloat16* sA, const __hip_bfloat16* sB,
    int wr, int wc, int r15, int khi, bf16x8 (&af)[4][2], bf16x8 (&bf)[4][2]) {
#pragma unroll
  for (int m = 0; m < 4; ++m)
#pragma unroll
    for (int kk = 0; kk < 2; ++kk) {
      const int row = wr * 64 + m * 16 + r15;
      const int slot = (kk * 4 + khi) ^ (row & 7);
      af[m][kk] = *reinterpret_cast<const bf16x8*>(&sA[row * 64 + slot * 8]);
    }
#pragma unroll
  for (int n = 0; n < 4; ++n)
#pragma unroll
    for (int kk = 0; kk < 2; ++kk) {
      const int row = wc * 64 + n * 16 + r15;
      const int slot = (kk * 4 + khi) ^ (row & 7);
      bf[n][kk] = *reinterpret_cast<const bf16x8*>(&sB[row * 64 + slot * 8]);
    }
}

__device__ __forceinline__ void do_mfma(
    const bf16x8 (&af)[4][2], const bf16x8 (&bf)[4][2], f32x4 (&acc)[4][4]) {
#pragma unroll
  for (int kk = 0; kk < 2; ++kk)
#pragma unroll
    for (int m = 0; m < 4; ++m)
#pragma unroll
      for (int n = 0; n < 4; ++n)
        acc[m][n] = __builtin_amdgcn_mfma_f32_16x16x32_bf16(
            af[m][kk], bf[n][kk], acc[m][n], 0, 0, 0);
}

// ---------------------------------------------------------------------------
// Kernel 1: psi MFMA GEMM (unchanged, proven).
// ---------------------------------------------------------------------------
__global__ __launch_bounds__(NT)
void psi_mfma(const __hip_bfloat16* __restrict__ wb,
              const __hip_bfloat16* __restrict__ DT,
              __hip_bfloat16* __restrict__ PT) {
  const int m0 = blockIdx.x * 128, n0 = blockIdx.y * 128;

  __shared__ __hip_bfloat16 sA[2][128 * 64];
  __shared__ __hip_bfloat16 sB[2][128 * 64];

  const int tid = threadIdx.x;
  const int lane = tid & 63, wave = tid >> 6;
  const int wr = wave & 1, wc = wave >> 1;
  const int r15 = lane & 15, khi = lane >> 4;

  f32x4 acc[4][4] = {};
  bf16x8 af[4][2], bf[4][2];

  stage_tile(wb, DT, 512, 0, m0, n0, tid, wave, sA[0], sB[0]);
  __syncthreads();
  int cur = 0;
  for (int t = 0; t < 8; ++t) {
    if (t + 1 < 8)
      stage_tile(wb, DT, 512, (t + 1) << 6, m0, n0, tid, wave, sA[cur ^ 1], sB[cur ^ 1]);
    load_frags(sA[cur], sB[cur], wr, wc, r15, khi, af, bf);
    do_mfma(af, bf, acc);
    if (t + 1 < 8) { __syncthreads(); cur ^= 1; }
  }

#pragma unroll
  for (int n = 0; n < 4; ++n) {
    const int s = n0 + wc * 64 + n * 16 + r15;
    if (s >= 286) continue;
    int off, d;
    decode_s(s, off, d);
    const int rel = s - off;
    const int u = rel / d, v = rel - u * d;
    const float scale = 1.0f / (256.0f * sqrtf((float)d));
    __hip_bfloat16* Pl = PT + off * 16384;
    const int Kd = 128 * d;
#pragma unroll
    for (int m = 0; m < 4; ++m)
#pragma unroll
      for (int j = 0; j < 4; ++j) {
        const int row = m0 + wr * 64 + m * 16 + khi * 4 + j;
        const int x = row >> 7, y = row & 127;
        Pl[(y * d + v) * Kd + (x * d + u)] = __float2bfloat16(acc[m][n][j] * scale);
      }
  }
}

// ---------------------------------------------------------------------------
// Kernel 2: main GEMM — exact R8 structure (runtime-d, dbuf, VGPR-lean).
// 1144 blocks, longest degree first. No swizzle, no extra launch bounds.
// ---------------------------------------------------------------------------
__global__ __launch_bounds__(NT)
void main_gemm(const __hip_bfloat16* __restrict__ Aall,
               const __hip_bfloat16* __restrict__ PTall,
               float* __restrict__ out) {
  int bx = blockIdx.x;
  int off, d;
  if (bx < 484)       { off = 165; d = 11; }
  else if (bx < 808)  { off = 84;  d = 9;  bx -= 484; }
  else if (bx < 1004) { off = 35;  d = 7;  bx -= 808; }
  else if (bx < 1104) { off = 10;  d = 5;  bx -= 1004; }
  else if (bx < 1140) { off = 1;   d = 3;  bx -= 1104; }
  else                { off = 0;   d = 1;  bx -= 1140; }
  const int bm = bx % (4 * d);
  const int bn = bx / (4 * d);
  const int Kn = 128 * d;
  const __hip_bfloat16* A  = Aall  + 65536 * off;
  const __hip_bfloat16* BT = PTall + 16384 * off;
  const int m0 = bm * 128, n0 = bn * 128;

  __shared__ __hip_bfloat16 sA[2][128 * 64];
  __shared__ __hip_bfloat16 sB[2][128 * 64];

  const int tid = threadIdx.x;
  const int lane = tid & 63, wave = tid >> 6;
  const int wr = wave & 1, wc = wave >> 1;
  const int r15 = lane & 15, khi = lane >> 4;

  f32x4 acc[4][4] = {};
  bf16x8 af[4][2], bf[4][2];

  const int nk = Kn >> 6;
  stage_tile(A, BT, Kn, 0, m0, n0, tid, wave, sA[0], sB[0]);
  __syncthreads();
  int cur = 0;
  for (int t = 0; t < nk; ++t) {
    if (t + 1 < nk)
      stage_tile(A, BT, Kn, (t + 1) << 6, m0, n0, tid, wave, sA[cur ^ 1], sB[cur ^ 1]);
    load_frags(sA[cur], sB[cur], wr, wc, r15, khi, af, bf);
    do_mfma(af, bf, acc);
    if (t + 1 < nk) { __syncthreads(); cur ^= 1; }
  }

  // Epilogue: row m=(b,i), col n=(yo,v) -> out[b][yo][off + v*d + i]
  int yo4[4], v4[4];
#pragma unroll
  for (int n = 0; n < 4; ++n) {
    const int col = n0 + wc * 64 + n * 16 + r15;
    yo4[n] = col / d;
    v4[n] = col - yo4[n] * d;
  }
#pragma unroll
  for (int m = 0; m < 4; ++m)
#pragma unroll
    for (int j = 0; j < 4; ++j) {
      const int row = m0 + wr * 64 + m * 16 + khi * 4 + j;
      const int bb = row / d, i = row - bb * d;
      float* orow = out + (size_t)bb * 36608 + off + i;
#pragma unroll
      for (int n = 0; n < 4; ++n)
        orow[yo4[n] * 286 + v4[n] * d] = acc[m][n][j];
    }
}

// ---------------------------------------------------------------------------
extern "C" void kernel_launch(void* const* d_in, const int* in_sizes, int n_in,
                              void* d_out, int out_size, void* d_ws, size_t ws_size,
                              hipStream_t stream) {
  const float* x  = (const float*)d_in[0];  // (512,128,286)
  const float* w  = (const float*)d_in[1];  // (128,128,512)
  const float* Dm = (const float*)d_in[2];  // (512,286)
  float* out = (float*)d_out;               // (512,128,286)

  // Workspace (bf16 elems): PT 16384*286 ; A 65536*286 ; wb 16384*512 ;
  // DT 384*512.
  __hip_bfloat16* PT = (__hip_bfloat16*)d_ws;
  __hip_bfloat16* A  = PT + 16384 * 286;
  __hip_bfloat16* wb = A + 65536 * 286;
  __hip_bfloat16* DT = wb + 16384 * 512;

  prep_all<<<dim3(7936), dim3(NT), 0, stream>>>(w, Dm, x, wb, DT, A);
  psi_mfma<<<dim3(128, 3), dim3(NT), 0, stream>>>(wb, DT, PT);
  main_gemm<<<dim3(1144), dim3(NT), 0, stream>>>(A, PT, out);
}